// Round 1
// baseline (1743.900 us; speedup 1.0000x reference)
//
#include <hip/hip_runtime.h>

#define WS 7
#define NTOK 49            // tokens per window
#define NH 16
#define DIM 512
#define HD 32              // head dim
#define HPB 4              // heads per block (1 per wave)
#define SCALE 0.17677669529663687f   // 32^-0.5

// qkv: [3, 32, 56, 56, 512] f32
// mask: [64, 49, 49] f32
// bias_table: [169, 16] f32
// out: [2048, 49, 512] f32
__global__ __launch_bounds__(256) void winattn_kernel(
    const float* __restrict__ qkv,
    const float* __restrict__ mask,
    const float* __restrict__ bias_table,
    float* __restrict__ out)
{
    const int bx   = blockIdx.x;      // 0..8191
    const int win  = bx >> 2;         // 0..2047
    const int hg   = bx & 3;
    const int tid  = threadIdx.x;
    const int wave = tid >> 6;
    const int lane = tid & 63;
    const int head = hg * HPB + wave;

    const int b  = win >> 6;          // image index
    const int w  = win & 63;          // window within image
    const int wr = w >> 3;
    const int wc = w & 7;

    __shared__ float mask_lds[NTOK * NTOK];
    __shared__ float bias_lds[HPB][176];

    // stage this window's mask (block-cooperative, coalesced)
    for (int t = tid; t < NTOK * NTOK; t += 256)
        mask_lds[t] = mask[(size_t)w * NTOK * NTOK + t];
    // stage this head's bias column (169 entries)
    for (int r = lane; r < 169; r += 64)
        bias_lds[wave][r] = bias_table[r * NH + head];

    const int n   = (lane < NTOK) ? lane : 0;   // query token (clamped for idle lanes)
    const int i_n = n / 7, j_n = n % 7;
    const int base_n = i_n * 13 + j_n;          // rel-pos row base

    const size_t plane = (size_t)32 * 56 * 56 * 512;
    // window origin pointers (head slice)
    const size_t worg = ((((size_t)b * 56) + wr * 7) * 56 + wc * 7) * 512 + head * HD;
    const float* qrow = qkv + worg + ((size_t)(i_n * 56 + j_n)) * 512;
    const float* kwin = qkv + plane + worg;
    const float* vwin = qkv + 2 * plane + worg;

    // load Q row for this lane: 32 contiguous floats
    float q[HD];
    #pragma unroll
    for (int d4 = 0; d4 < 8; ++d4) {
        float4 t = *(const float4*)(qrow + d4 * 4);
        q[d4 * 4 + 0] = t.x; q[d4 * 4 + 1] = t.y;
        q[d4 * 4 + 2] = t.z; q[d4 * 4 + 3] = t.w;
    }

    __syncthreads();

    // ---- QK^T + bias + mask, row n fully in-lane ----
    float s[NTOK];
    #pragma unroll
    for (int m = 0; m < NTOK; ++m) {
        const int im = m / 7, jm = m % 7;
        const float* kr = kwin + (size_t)(im * 56 + jm) * 512;   // wave-uniform address
        float a0 = 0.f, a1 = 0.f, a2 = 0.f, a3 = 0.f;
        #pragma unroll
        for (int d4 = 0; d4 < 8; ++d4) {
            float4 kv = *(const float4*)(kr + d4 * 4);
            a0 = __builtin_fmaf(q[d4 * 4 + 0], kv.x, a0);
            a1 = __builtin_fmaf(q[d4 * 4 + 1], kv.y, a1);
            a2 = __builtin_fmaf(q[d4 * 4 + 2], kv.z, a2);
            a3 = __builtin_fmaf(q[d4 * 4 + 3], kv.w, a3);
        }
        const float dot = (a0 + a1) + (a2 + a3);
        const int cm = (6 - im) * 13 + (6 - jm);                 // compile-time constant
        s[m] = dot * SCALE + bias_lds[wave][base_n + cm] + mask_lds[n * NTOK + m];
    }

    // ---- softmax (lane-local) ----
    float mx = s[0];
    #pragma unroll
    for (int m = 1; m < NTOK; ++m) mx = fmaxf(mx, s[m]);
    float sum = 0.f;
    #pragma unroll
    for (int m = 0; m < NTOK; ++m) { s[m] = __expf(s[m] - mx); sum += s[m]; }
    const float inv = 1.0f / sum;

    // ---- P·V ----
    float o[HD];
    #pragma unroll
    for (int d = 0; d < HD; ++d) o[d] = 0.f;
    #pragma unroll
    for (int m = 0; m < NTOK; ++m) {
        const float* vr = vwin + (size_t)((m / 7) * 56 + (m % 7)) * 512; // wave-uniform
        const float p = s[m];
        #pragma unroll
        for (int d4 = 0; d4 < 8; ++d4) {
            float4 vv = *(const float4*)(vr + d4 * 4);
            o[d4 * 4 + 0] = __builtin_fmaf(p, vv.x, o[d4 * 4 + 0]);
            o[d4 * 4 + 1] = __builtin_fmaf(p, vv.y, o[d4 * 4 + 1]);
            o[d4 * 4 + 2] = __builtin_fmaf(p, vv.z, o[d4 * 4 + 2]);
            o[d4 * 4 + 3] = __builtin_fmaf(p, vv.w, o[d4 * 4 + 3]);
        }
    }

    // ---- write out[win, n, head*32 : head*32+32] ----
    if (lane < NTOK) {
        float* op = out + ((size_t)win * NTOK + lane) * DIM + head * HD;
        #pragma unroll
        for (int d4 = 0; d4 < 8; ++d4) {
            float4 t;
            t.x = o[d4 * 4 + 0] * inv; t.y = o[d4 * 4 + 1] * inv;
            t.z = o[d4 * 4 + 2] * inv; t.w = o[d4 * 4 + 3] * inv;
            *(float4*)(op + d4 * 4) = t;
        }
    }
}

extern "C" void kernel_launch(void* const* d_in, const int* in_sizes, int n_in,
                              void* d_out, int out_size, void* d_ws, size_t ws_size,
                              hipStream_t stream) {
    const float* qkv        = (const float*)d_in[0];
    const float* mask       = (const float*)d_in[1];
    const float* bias_table = (const float*)d_in[2];
    float* out = (float*)d_out;

    const int nblocks = 2048 * (NH / HPB);   // 8192 blocks: (window, head-group)
    winattn_kernel<<<nblocks, 256, 0, stream>>>(qkv, mask, bias_table, out);
}

// Round 2
// 409.167 us; speedup vs baseline: 4.2621x; 4.2621x over previous
//
#include <hip/hip_runtime.h>

#define WS 7
#define NTOK 49            // tokens per window
#define NH 16
#define DIM 512
#define HD 32              // head dim
#define HPB 4              // heads per block (1 per wave)
#define SCALE 0.17677669529663687f   // 32^-0.5

// qkv: [3, 32, 56, 56, 512] f32
// mask: [64, 49, 49] f32
// bias_table: [169, 16] f32
// out: [2048, 49, 512] f32
__global__ __launch_bounds__(256, 2) void winattn_kernel(
    const float* __restrict__ qkv,
    const float* __restrict__ mask,
    const float* __restrict__ bias_table,
    float* __restrict__ out)
{
    const int bx   = blockIdx.x;      // 0..8191
    const int win  = bx >> 2;         // 0..2047
    const int hg   = bx & 3;          // head group (4 heads)
    const int tid  = threadIdx.x;
    const int wave = tid >> 6;
    const int lane = tid & 63;
    const int head = hg * HPB + wave;

    const int b  = win >> 6;          // image index
    const int w  = win & 63;          // window within image
    const int wr = w >> 3;
    const int wc = w & 7;

    __shared__ float k_lds[NTOK][128];        // 4 heads' K rows
    __shared__ float v_lds[NTOK][128];        // 4 heads' V rows
    __shared__ float mask_lds[NTOK * NTOK];
    __shared__ float bias_lds[HPB][176];

    const size_t plane = (size_t)32 * 56 * 56 * 512;
    // window origin for this head-group's 128-channel slice
    const size_t worg_grp = ((((size_t)b * 56) + wr * 7) * 56 + wc * 7) * 512 + hg * (HPB * HD);
    const float* kg = qkv + plane + worg_grp;
    const float* vg = qkv + 2 * plane + worg_grp;

    // ---- block-cooperative coalesced staging of K,V (49 x 128 f32 each) ----
    for (int e4 = tid; e4 < NTOK * 32; e4 += 256) {
        const int token = e4 >> 5;          // 32 float4 per token
        const int c4    = e4 & 31;
        const int im = token / 7, jm = token - im * 7;
        const size_t off = (size_t)(im * 56 + jm) * 512 + c4 * 4;
        *(float4*)&k_lds[token][c4 * 4] = *(const float4*)(kg + off);
        *(float4*)&v_lds[token][c4 * 4] = *(const float4*)(vg + off);
    }
    // stage this window's mask
    for (int t = tid; t < NTOK * NTOK; t += 256)
        mask_lds[t] = mask[(size_t)w * NTOK * NTOK + t];
    // stage per-head bias column (169 entries)
    for (int r = lane; r < 169; r += 64)
        bias_lds[wave][r] = bias_table[r * NH + head];

    const int n   = (lane < NTOK) ? lane : 0;   // query token (clamped for idle lanes)
    const int i_n = n / 7, j_n = n % 7;
    const int base_n = i_n * 13 + j_n;          // rel-pos row base

    // per-lane Q row: 32 contiguous floats
    const float* qrow = qkv + worg_grp + ((size_t)(i_n * 56 + j_n)) * 512 + wave * HD;
    float q[HD];
    #pragma unroll
    for (int d4 = 0; d4 < 8; ++d4) {
        float4 t = *(const float4*)(qrow + d4 * 4);
        q[d4 * 4 + 0] = t.x; q[d4 * 4 + 1] = t.y;
        q[d4 * 4 + 2] = t.z; q[d4 * 4 + 3] = t.w;
    }

    __syncthreads();

    const int kbase = wave * HD;

    // ---- QK^T + bias + mask; row n fully in-lane; K rows broadcast from LDS ----
    float s[NTOK];
    #pragma unroll
    for (int m = 0; m < NTOK; ++m) {
        const int im = m / 7, jm = m % 7;
        const float* kr = &k_lds[m][kbase];       // wave-uniform LDS address
        float a0 = 0.f, a1 = 0.f, a2 = 0.f, a3 = 0.f;
        #pragma unroll
        for (int d4 = 0; d4 < 8; ++d4) {
            float4 kv = *(const float4*)(kr + d4 * 4);
            a0 = __builtin_fmaf(q[d4 * 4 + 0], kv.x, a0);
            a1 = __builtin_fmaf(q[d4 * 4 + 1], kv.y, a1);
            a2 = __builtin_fmaf(q[d4 * 4 + 2], kv.z, a2);
            a3 = __builtin_fmaf(q[d4 * 4 + 3], kv.w, a3);
        }
        const float dot = (a0 + a1) + (a2 + a3);
        const int cm = (6 - im) * 13 + (6 - jm);  // compile-time constant
        s[m] = dot * SCALE + bias_lds[wave][base_n + cm] + mask_lds[n * NTOK + m];
    }

    // ---- softmax (lane-local) ----
    float mx = s[0];
    #pragma unroll
    for (int m = 1; m < NTOK; ++m) mx = fmaxf(mx, s[m]);
    float sum = 0.f;
    #pragma unroll
    for (int m = 0; m < NTOK; ++m) { s[m] = __expf(s[m] - mx); sum += s[m]; }
    const float inv = 1.0f / sum;

    // ---- P·V from LDS ----
    float o[HD];
    #pragma unroll
    for (int d = 0; d < HD; ++d) o[d] = 0.f;
    #pragma unroll
    for (int m = 0; m < NTOK; ++m) {
        const float* vr = &v_lds[m][kbase];       // wave-uniform LDS address
        const float p = s[m];
        #pragma unroll
        for (int d4 = 0; d4 < 8; ++d4) {
            float4 vv = *(const float4*)(vr + d4 * 4);
            o[d4 * 4 + 0] = __builtin_fmaf(p, vv.x, o[d4 * 4 + 0]);
            o[d4 * 4 + 1] = __builtin_fmaf(p, vv.y, o[d4 * 4 + 1]);
            o[d4 * 4 + 2] = __builtin_fmaf(p, vv.z, o[d4 * 4 + 2]);
            o[d4 * 4 + 3] = __builtin_fmaf(p, vv.w, o[d4 * 4 + 3]);
        }
    }

    // ---- write out[win, n, head*32 : head*32+32] ----
    if (lane < NTOK) {
        float* op = out + ((size_t)win * NTOK + lane) * DIM + head * HD;
        #pragma unroll
        for (int d4 = 0; d4 < 8; ++d4) {
            float4 t;
            t.x = o[d4 * 4 + 0] * inv; t.y = o[d4 * 4 + 1] * inv;
            t.z = o[d4 * 4 + 2] * inv; t.w = o[d4 * 4 + 3] * inv;
            *(float4*)(op + d4 * 4) = t;
        }
    }
}

extern "C" void kernel_launch(void* const* d_in, const int* in_sizes, int n_in,
                              void* d_out, int out_size, void* d_ws, size_t ws_size,
                              hipStream_t stream) {
    const float* qkv        = (const float*)d_in[0];
    const float* mask       = (const float*)d_in[1];
    const float* bias_table = (const float*)d_in[2];
    float* out = (float*)d_out;

    const int nblocks = 2048 * (NH / HPB);   // 8192 blocks: (window, head-group)
    winattn_kernel<<<nblocks, 256, 0, stream>>>(qkv, mask, bias_table, out);
}

// Round 3
// 259.212 us; speedup vs baseline: 6.7277x; 1.5785x over previous
//
#include <hip/hip_runtime.h>

#define NTOK 49
#define NH 16
#define DIM 512
#define HD 32
#define HPB 4
#define SCALE 0.17677669529663687f   // 32^-0.5

typedef __attribute__((ext_vector_type(8))) short short8;
typedef __attribute__((ext_vector_type(16))) float f32x16;

__device__ __forceinline__ unsigned short f2b(float x) {
    union { float f; unsigned u; } v; v.f = x;
    unsigned u = v.u;
    u += 0x7fffu + ((u >> 16) & 1u);          // RNE to bf16
    return (unsigned short)(u >> 16);
}

__device__ __forceinline__ unsigned long long pack4(float4 v) {
    unsigned lo = (unsigned)f2b(v.x) | ((unsigned)f2b(v.y) << 16);
    unsigned hi = (unsigned)f2b(v.z) | ((unsigned)f2b(v.w) << 16);
    return (unsigned long long)lo | ((unsigned long long)hi << 32);
}

// qkv: [3,32,56,56,512] f32 | mask: [64,49,49] f32 | bias_table: [169,16] f32
// out: [2048,49,512] f32
__global__ __launch_bounds__(256, 2) void winattn_mfma(
    const float* __restrict__ qkv,
    const float* __restrict__ mask,
    const float* __restrict__ bias_table,
    float* __restrict__ out)
{
    // chunked layout: [head][d-chunk(8 bf16)][token][8] -> frag reads are
    // 16B-consecutive across lanes (conflict-free)
    __shared__ __align__(16) unsigned short Qc[HPB][4][64][8];
    __shared__ __align__(16) unsigned short Kc[HPB][4][64][8];
    __shared__ __align__(16) unsigned short Vr[HPB][64][32];   // row-major [token][d]
    __shared__ float maskl[NTOK][52];
    __shared__ float biasl[HPB][176];

    const int bx   = blockIdx.x;
    const int win  = bx >> 2;
    const int hg   = bx & 3;
    const int tid  = threadIdx.x;
    const int wave = tid >> 6;
    const int lane = tid & 63;
    const int ln   = lane & 31;
    const int h    = lane >> 5;
    const int head0 = hg * HPB;
    const int head  = head0 + wave;

    const int b  = win >> 6;
    const int w  = win & 63;
    const int wr = w >> 3, wc = w & 7;

    const size_t plane = (size_t)32 * 56 * 56 * 512;

    // ---- staging: Q,K (chunked bf16), V (row-major bf16); zero-pad tokens 49..63 ----
    for (int e = tid; e < 2048; e += 256) {     // 4 heads * 64 tokens * 8 float4-slots
        const int hh = e >> 9;
        const int t  = (e >> 3) & 63;
        const int d4 = e & 7;
        unsigned long long qz = 0, kz = 0, vz = 0;
        if (t < NTOK) {
            const int i = t / 7, j = t - i * 7;
            const size_t goff = (((size_t)(b * 56 + wr * 7 + i)) * 56 + (wc * 7 + j)) * 512
                              + (head0 + hh) * HD + d4 * 4;
            qz = pack4(*(const float4*)(qkv + goff));
            kz = pack4(*(const float4*)(qkv + plane + goff));
            vz = pack4(*(const float4*)(qkv + 2 * plane + goff));
        }
        *(unsigned long long*)&Qc[hh][d4 >> 1][t][(d4 & 1) * 4] = qz;
        *(unsigned long long*)&Kc[hh][d4 >> 1][t][(d4 & 1) * 4] = kz;
        *(unsigned long long*)&Vr[hh][t][d4 * 4] = vz;
    }
    for (int e = tid; e < NTOK * NTOK; e += 256) {
        const int n = e / NTOK, m = e - n * NTOK;
        maskl[n][m] = mask[(size_t)w * (NTOK * NTOK) + e];
    }
    for (int e = tid; e < 169 * HPB; e += 256) {
        const int hh = e / 169, r = e - hh * 169;
        biasl[hh][r] = bias_table[r * NH + head0 + hh];
    }
    __syncthreads();

    // ---- QK^T swapped: S'[m][n] = K . Q^T   (A=K rows m, B=Q^T cols n) ----
    f32x16 zer;
    #pragma unroll
    for (int i = 0; i < 16; ++i) zer[i] = 0.f;
    f32x16 acc[2][2];                    // [mt][nt]
    acc[0][0] = zer; acc[0][1] = zer; acc[1][0] = zer; acc[1][1] = zer;

    #pragma unroll
    for (int ks = 0; ks < 2; ++ks) {     // K-dim = head_dim 32 = 2 x 16
        const short8 kf0 = *(const short8*)&Kc[wave][2 * ks + h][ln][0];
        const short8 kf1 = *(const short8*)&Kc[wave][2 * ks + h][32 + ln][0];
        const short8 qf0 = *(const short8*)&Qc[wave][2 * ks + h][ln][0];
        const short8 qf1 = *(const short8*)&Qc[wave][2 * ks + h][32 + ln][0];
        acc[0][0] = __builtin_amdgcn_mfma_f32_32x32x16_bf16(kf0, qf0, acc[0][0], 0, 0, 0);
        acc[0][1] = __builtin_amdgcn_mfma_f32_32x32x16_bf16(kf0, qf1, acc[0][1], 0, 0, 0);
        acc[1][0] = __builtin_amdgcn_mfma_f32_32x32x16_bf16(kf1, qf0, acc[1][0], 0, 0, 0);
        acc[1][1] = __builtin_amdgcn_mfma_f32_32x32x16_bf16(kf1, qf1, acc[1][1], 0, 0, 0);
    }

    // ---- logits + softmax (per n-column, lane-local + one shfl_xor(32)) ----
    float p[2][2][16];                   // [nt][mt][reg]
    #pragma unroll
    for (int nt = 0; nt < 2; ++nt) {
        const int n  = 32 * nt + ln;
        const int nc = n < NTOK ? n : NTOK - 1;
        const int i_n = nc / 7;
        const int tn  = nc + 6 * i_n + 84;   // (i*13+j) + 84
        float mx = -3.0e38f;
        #pragma unroll
        for (int mt = 0; mt < 2; ++mt) {
            #pragma unroll
            for (int r = 0; r < 16; ++r) {
                const int mb  = 32 * mt + (r & 3) + 8 * (r >> 2);   // m for h=0
                const int m0  = mb, m1 = mb + 4;                    // m per half
                const int mc0 = m0 < NTOK ? m0 : NTOK - 1;
                const int mc1 = m1 < NTOK ? m1 : NTOK - 1;
                const int tm0 = mc0 + 6 * (mc0 / 7);                // compile-time
                const int tm1 = mc1 + 6 * (mc1 / 7);                // compile-time
                const int mc  = h ? mc1 : mc0;
                const int tm  = h ? tm1 : tm0;
                float s = acc[mt][nt][r] * SCALE + biasl[wave][tn - tm] + maskl[nc][mc];
                const bool dead = h ? (m1 >= NTOK) : (m0 >= NTOK);
                s = dead ? -3.0e38f : s;
                p[nt][mt][r] = s;
                mx = fmaxf(mx, s);
            }
        }
        mx = fmaxf(mx, __shfl_xor(mx, 32));
        float sum = 0.f;
        #pragma unroll
        for (int mt = 0; mt < 2; ++mt) {
            #pragma unroll
            for (int r = 0; r < 16; ++r) {
                const float ev = __expf(p[nt][mt][r] - mx);
                p[nt][mt][r] = ev;
                sum += ev;
            }
        }
        sum += __shfl_xor(sum, 32);
        const float inv = 1.0f / sum;
        #pragma unroll
        for (int mt = 0; mt < 2; ++mt) {
            #pragma unroll
            for (int r = 0; r < 16; ++r) p[nt][mt][r] *= inv;
        }
    }

    // ---- PV: O[n][d] = sum_m P'[m][n] V[m][d]  (A = P^T via shfl redistribution, B = V) ----
    f32x16 oacc[2];
    oacc[0] = zer; oacc[1] = zer;
    #pragma unroll
    for (int ksv = 0; ksv < 4; ++ksv) {  // m: 4 x 16
        short8 vf;
        #pragma unroll
        for (int j = 0; j < 8; ++j)
            vf[j] = (short)Vr[wave][16 * ksv + 8 * h + j][ln];
        const int mt = ksv >> 1;
        #pragma unroll
        for (int nt = 0; nt < 2; ++nt) {
            short8 af;
            #pragma unroll
            for (int jj = 0; jj < 4; ++jj) {
                const int base = jj + 8 * (ksv & 1);
                const float v0 = p[nt][mt][base];       // reg for h=0 consumer
                const float v1 = p[nt][mt][base + 4];   // reg for h=1 consumer
                const float offer = h ? v0 : v1;        // reg the OTHER half needs
                const float oth = __shfl_xor(offer, 32);
                af[jj]     = (short)f2b(h ? oth : v0);  // element j   (src half 0)
                af[jj + 4] = (short)f2b(h ? v1 : oth);  // element j+4 (src half 1)
            }
            oacc[nt] = __builtin_amdgcn_mfma_f32_32x32x16_bf16(af, vf, oacc[nt], 0, 0, 0);
        }
    }

    // ---- store: D[row=n][col=d=ln] ----
    const size_t obase = ((size_t)win * NTOK) * DIM + head * HD + ln;
    #pragma unroll
    for (int nt = 0; nt < 2; ++nt) {
        #pragma unroll
        for (int r = 0; r < 16; ++r) {
            const int nb = 32 * nt + (r & 3) + 8 * (r >> 2);
            const int n  = h ? nb + 4 : nb;
            if (n < NTOK)
                out[obase + (size_t)n * DIM] = oacc[nt][r];
        }
    }
}

extern "C" void kernel_launch(void* const* d_in, const int* in_sizes, int n_in,
                              void* d_out, int out_size, void* d_ws, size_t ws_size,
                              hipStream_t stream) {
    const float* qkv        = (const float*)d_in[0];
    const float* mask       = (const float*)d_in[1];
    const float* bias_table = (const float*)d_in[2];
    float* out = (float*)d_out;

    const int nblocks = 2048 * (NH / HPB);   // (window, head-group)
    winattn_mfma<<<nblocks, 256, 0, stream>>>(qkv, mask, bias_table, out);
}

// Round 4
// 201.048 us; speedup vs baseline: 8.6740x; 1.2893x over previous
//
#include <hip/hip_runtime.h>

#define NTOK 49
#define NH 16
#define DIM 512
#define HD 32
#define HPB 4
#define SCALE 0.17677669529663687f   // 32^-0.5

typedef __attribute__((ext_vector_type(8))) short short8;
typedef __attribute__((ext_vector_type(16))) float f32x16;

__device__ __forceinline__ unsigned short f2b(float x) {
    union { float f; unsigned u; } v; v.f = x;
    unsigned u = v.u;
    u += 0x7fffu + ((u >> 16) & 1u);          // RNE to bf16
    return (unsigned short)(u >> 16);
}

__device__ __forceinline__ unsigned long long pack4(float4 v) {
    unsigned lo = (unsigned)f2b(v.x) | ((unsigned)f2b(v.y) << 16);
    unsigned hi = (unsigned)f2b(v.z) | ((unsigned)f2b(v.w) << 16);
    return (unsigned long long)lo | ((unsigned long long)hi << 32);
}

__device__ __forceinline__ short8 pack8(float4 a, float4 b) {
    short8 r;
    r[0] = (short)f2b(a.x); r[1] = (short)f2b(a.y);
    r[2] = (short)f2b(a.z); r[3] = (short)f2b(a.w);
    r[4] = (short)f2b(b.x); r[5] = (short)f2b(b.y);
    r[6] = (short)f2b(b.z); r[7] = (short)f2b(b.w);
    return r;
}

// qkv: [3,32,56,56,512] f32 | mask: [64,49,49] f32 | bias_table: [169,16] f32
// out: [2048,49,512] f32
__global__ __launch_bounds__(256, 3) void winattn_mfma(
    const float* __restrict__ qkv,
    const float* __restrict__ mask,
    const float* __restrict__ bias_table,
    float* __restrict__ out)
{
    __shared__ __align__(16) unsigned short Vr[HPB][64][32];   // V row-major bf16
    __shared__ float maskl[NTOK][52];
    __shared__ float biasl[HPB][176];

    const int bx   = blockIdx.x;
    const int win  = bx >> 2;
    const int hg   = bx & 3;
    const int tid  = threadIdx.x;
    const int wave = tid >> 6;
    const int lane = tid & 63;
    const int ln   = lane & 31;
    const int h    = lane >> 5;
    const int head0 = hg * HPB;
    const int head  = head0 + wave;

    const int b  = win >> 6;
    const int w  = win & 63;
    const int wr = w >> 3, wc = w & 7;

    const size_t plane = (size_t)32 * 56 * 56 * 512;

    // ---- V staging (coalesced, bf16, zero-pad tokens 49..63) ----
    for (int e = tid; e < HPB * 64 * 8; e += 256) {
        const int hh = e >> 9;
        const int t  = (e >> 3) & 63;
        const int d4 = e & 7;
        unsigned long long vz = 0;
        if (t < NTOK) {
            const int i = t / 7, j = t - i * 7;
            const size_t goff = (((size_t)(b * 56 + wr * 7 + i)) * 56 + (wc * 7 + j)) * 512
                              + (head0 + hh) * HD + d4 * 4;
            vz = pack4(*(const float4*)(qkv + 2 * plane + goff));
        }
        *(unsigned long long*)&Vr[hh][t][d4 * 4] = vz;
    }
    for (int e = tid; e < NTOK * NTOK; e += 256) {
        const int n = e / NTOK, m = e - n * NTOK;
        maskl[n][m] = mask[(size_t)w * (NTOK * NTOK) + e];
    }
    for (int e = tid; e < 169 * HPB; e += 256) {
        const int hh = e / 169, r = e - hh * 169;
        biasl[hh][r] = bias_table[r * NH + head0 + hh];
    }

    // ---- Q/K fragments straight from global (per-lane, bf16 in-register) ----
    // lane (ln,h): tokens t0=ln (tile 0), t1=min(32+ln,48) (tile 1, clamped; dead
    // rows/cols are masked or never stored). chunks c = 2*ks+h -> f32 offsets
    // {8h, 8h+4, 16+8h, 16+8h+4}.
    const int t0 = ln;
    const int t1 = (32 + ln <= 48) ? (32 + ln) : 48;
    const size_t wbase = (((size_t)(b * 56 + wr * 7)) * 56 + wc * 7) * 512 + head * HD;

    short8 qfr[2][2], kfr[2][2];   // [token-tile][ks]
    #pragma unroll
    for (int tt = 0; tt < 2; ++tt) {
        const int t  = tt ? t1 : t0;
        const int i  = t / 7, j = t - i * 7;
        const float* qp = qkv + wbase + (size_t)(i * 56 + j) * 512 + h * 8;
        const float* kp = qp + plane;
        float4 q0 = *(const float4*)(qp);
        float4 q1 = *(const float4*)(qp + 4);
        float4 q2 = *(const float4*)(qp + 16);
        float4 q3 = *(const float4*)(qp + 20);
        float4 k0 = *(const float4*)(kp);
        float4 k1 = *(const float4*)(kp + 4);
        float4 k2 = *(const float4*)(kp + 16);
        float4 k3 = *(const float4*)(kp + 20);
        qfr[tt][0] = pack8(q0, q1);  qfr[tt][1] = pack8(q2, q3);
        kfr[tt][0] = pack8(k0, k1);  kfr[tt][1] = pack8(k2, k3);
    }

    __syncthreads();

    // ---- QK^T swapped: S'[m][n] = K . Q^T ----
    f32x16 zer;
    #pragma unroll
    for (int i = 0; i < 16; ++i) zer[i] = 0.f;
    f32x16 acc[2][2];                    // [mt][nt]
    acc[0][0] = zer; acc[0][1] = zer; acc[1][0] = zer; acc[1][1] = zer;
    #pragma unroll
    for (int ks = 0; ks < 2; ++ks) {
        acc[0][0] = __builtin_amdgcn_mfma_f32_32x32x16_bf16(kfr[0][ks], qfr[0][ks], acc[0][0], 0, 0, 0);
        acc[0][1] = __builtin_amdgcn_mfma_f32_32x32x16_bf16(kfr[0][ks], qfr[1][ks], acc[0][1], 0, 0, 0);
        acc[1][0] = __builtin_amdgcn_mfma_f32_32x32x16_bf16(kfr[1][ks], qfr[0][ks], acc[1][0], 0, 0, 0);
        acc[1][1] = __builtin_amdgcn_mfma_f32_32x32x16_bf16(kfr[1][ks], qfr[1][ks], acc[1][1], 0, 0, 0);
    }

    // ---- logits + softmax per n-tile; pack P to bf16 pairs for PV ----
    unsigned wpk[2][2][8];               // [nt][mt][g] : (p[ia], p[ia+4]) bf16x2
    #pragma unroll
    for (int nt = 0; nt < 2; ++nt) {
        const int n  = 32 * nt + ln;
        const int nc = n < NTOK ? n : NTOK - 1;
        const int i_n = nc / 7;
        const int tn  = nc + 6 * i_n + 84;          // (i*13+j) + 84
        float pl[2][16];
        float mx = -3.0e38f;
        #pragma unroll
        for (int mt = 0; mt < 2; ++mt) {
            #pragma unroll
            for (int r = 0; r < 16; ++r) {
                const int mb  = 32 * mt + (r & 3) + 8 * (r >> 2);
                const int m0  = mb, m1 = mb + 4;
                const int mc0 = m0 < NTOK ? m0 : NTOK - 1;
                const int mc1 = m1 < NTOK ? m1 : NTOK - 1;
                const int tm0 = mc0 + 6 * (mc0 / 7);   // compile-time
                const int tm1 = mc1 + 6 * (mc1 / 7);   // compile-time
                const int mc  = h ? mc1 : mc0;
                const int tm  = h ? tm1 : tm0;
                float s = acc[mt][nt][r] * SCALE + biasl[wave][tn - tm] + maskl[nc][mc];
                const bool dead = h ? (m1 >= NTOK) : (m0 >= NTOK);
                s = dead ? -3.0e38f : s;
                pl[mt][r] = s;
                mx = fmaxf(mx, s);
            }
        }
        mx = fmaxf(mx, __shfl_xor(mx, 32));
        float sum = 0.f;
        #pragma unroll
        for (int mt = 0; mt < 2; ++mt) {
            #pragma unroll
            for (int r = 0; r < 16; ++r) {
                const float ev = __expf(pl[mt][r] - mx);
                pl[mt][r] = ev;
                sum += ev;
            }
        }
        sum += __shfl_xor(sum, 32);
        const float inv = 1.0f / sum;
        #pragma unroll
        for (int mt = 0; mt < 2; ++mt) {
            #pragma unroll
            for (int g = 0; g < 8; ++g) {
                const int ia = (g < 4) ? g : g + 4;
                wpk[nt][mt][g] = (unsigned)f2b(pl[mt][ia] * inv)
                               | ((unsigned)f2b(pl[mt][ia + 4] * inv) << 16);
            }
        }
    }

    // ---- PV: O[n][d] = sum_m P'[m][n] V[m][d] ----
    f32x16 oacc[2];
    oacc[0] = zer; oacc[1] = zer;
    #pragma unroll
    for (int ksv = 0; ksv < 4; ++ksv) {
        short8 vf;
        #pragma unroll
        for (int j = 0; j < 8; ++j)
            vf[j] = (short)Vr[wave][16 * ksv + 8 * h + j][ln];
        const int mt = ksv >> 1;
        #pragma unroll
        for (int nt = 0; nt < 2; ++nt) {
            unsigned short alo[4], ahi[4];
            #pragma unroll
            for (int jj = 0; jj < 4; ++jj) {
                const unsigned W = wpk[nt][mt][(ksv & 1) * 4 + jj];
                const unsigned U = (unsigned)__shfl_xor((int)W, 32);
                alo[jj] = h ? (unsigned short)(U >> 16) : (unsigned short)(W & 0xffffu);
                ahi[jj] = h ? (unsigned short)(W >> 16) : (unsigned short)(U & 0xffffu);
            }
            short8 af;
            af[0] = (short)alo[0]; af[1] = (short)alo[1];
            af[2] = (short)alo[2]; af[3] = (short)alo[3];
            af[4] = (short)ahi[0]; af[5] = (short)ahi[1];
            af[6] = (short)ahi[2]; af[7] = (short)ahi[3];
            oacc[nt] = __builtin_amdgcn_mfma_f32_32x32x16_bf16(af, vf, oacc[nt], 0, 0, 0);
        }
    }

    // ---- store: D[row=n][col=d=ln] ----
    const size_t obase = ((size_t)win * NTOK) * DIM + head * HD + ln;
    #pragma unroll
    for (int nt = 0; nt < 2; ++nt) {
        #pragma unroll
        for (int r = 0; r < 16; ++r) {
            const int nb = 32 * nt + (r & 3) + 8 * (r >> 2);
            const int n  = h ? nb + 4 : nb;
            if (n < NTOK)
                out[obase + (size_t)n * DIM] = oacc[nt][r];
        }
    }
}

extern "C" void kernel_launch(void* const* d_in, const int* in_sizes, int n_in,
                              void* d_out, int out_size, void* d_ws, size_t ws_size,
                              hipStream_t stream) {
    const float* qkv        = (const float*)d_in[0];
    const float* mask       = (const float*)d_in[1];
    const float* bias_table = (const float*)d_in[2];
    float* out = (float*)d_out;

    const int nblocks = 2048 * (NH / HPB);   // (window, head-group)
    winattn_mfma<<<nblocks, 256, 0, stream>>>(qkv, mask, bias_table, out);
}

// Round 5
// 198.710 us; speedup vs baseline: 8.7761x; 1.0118x over previous
//
#include <hip/hip_runtime.h>

#define NTOK 49
#define NH 16
#define DIM 512
#define HD 32
#define HPB 4
#define SCALE 0.17677669529663687f   // 32^-0.5

typedef __attribute__((ext_vector_type(8))) short short8;
typedef __attribute__((ext_vector_type(16))) float f32x16;

__device__ __forceinline__ unsigned short f2b(float x) {
    union { float f; unsigned u; } v; v.f = x;
    unsigned u = v.u;
    u += 0x7fffu + ((u >> 16) & 1u);          // RNE to bf16
    return (unsigned short)(u >> 16);
}

__device__ __forceinline__ unsigned long long pack4(float4 v) {
    unsigned lo = (unsigned)f2b(v.x) | ((unsigned)f2b(v.y) << 16);
    unsigned hi = (unsigned)f2b(v.z) | ((unsigned)f2b(v.w) << 16);
    return (unsigned long long)lo | ((unsigned long long)hi << 32);
}

__device__ __forceinline__ short8 pack8(float4 a, float4 b) {
    short8 r;
    r[0] = (short)f2b(a.x); r[1] = (short)f2b(a.y);
    r[2] = (short)f2b(a.z); r[3] = (short)f2b(a.w);
    r[4] = (short)f2b(b.x); r[5] = (short)f2b(b.y);
    r[6] = (short)f2b(b.z); r[7] = (short)f2b(b.w);
    return r;
}

// qkv: [3,32,56,56,512] f32 | mask: [64,49,49] f32 | bias_table: [169,16] f32
// out: [2048,49,512] f32
__global__ __launch_bounds__(256, 4) void winattn_mfma(
    const float* __restrict__ qkv,
    const float* __restrict__ mask,
    const float* __restrict__ bias_table,
    float* __restrict__ out)
{
    __shared__ __align__(16) unsigned short Vr[HPB][64][32];   // V row-major bf16 (16 KB)
    __shared__ float maskl[NTOK * NTOK];   // flat, stride 49 (odd) -> conflict-free gathers
    __shared__ float biasl[HPB][176];
    __shared__ float invl[HPB][64];        // 1/rowsum per query token

    const int bx   = blockIdx.x;
    const int win  = bx >> 2;
    const int hg   = bx & 3;
    const int tid  = threadIdx.x;
    const int wave = tid >> 6;
    const int lane = tid & 63;
    const int ln   = lane & 31;
    const int h    = lane >> 5;
    const int head0 = hg * HPB;
    const int head  = head0 + wave;

    const int b  = win >> 6;
    const int w  = win & 63;
    const int wr = w >> 3, wc = w & 7;

    const size_t plane = (size_t)32 * 56 * 56 * 512;

    // ---- V staging (coalesced, bf16, zero-pad tokens 49..63) ----
    for (int e = tid; e < HPB * 64 * 8; e += 256) {
        const int hh = e >> 9;
        const int t  = (e >> 3) & 63;
        const int d4 = e & 7;
        unsigned long long vz = 0;
        if (t < NTOK) {
            const int i = t / 7, j = t - i * 7;
            const size_t goff = (((size_t)(b * 56 + wr * 7 + i)) * 56 + (wc * 7 + j)) * 512
                              + (head0 + hh) * HD + d4 * 4;
            vz = pack4(*(const float4*)(qkv + 2 * plane + goff));
        }
        *(unsigned long long*)&Vr[hh][t][d4 * 4] = vz;
    }
    // mask: pure linear copy (stride 49 preserved)
    for (int e = tid; e < NTOK * NTOK; e += 256)
        maskl[e] = mask[(size_t)w * (NTOK * NTOK) + e];
    for (int e = tid; e < 169 * HPB; e += 256) {
        const int hh = e / 169, r = e - hh * 169;
        biasl[hh][r] = bias_table[r * NH + head0 + hh];
    }

    // ---- Q/K fragments straight from global (per-lane, bf16 in-register) ----
    const int t0 = ln;
    const int t1 = (32 + ln <= 48) ? (32 + ln) : 48;
    const size_t wbase = (((size_t)(b * 56 + wr * 7)) * 56 + wc * 7) * 512 + head * HD;

    short8 qfr[2][2], kfr[2][2];   // [token-tile][ks]
    #pragma unroll
    for (int tt = 0; tt < 2; ++tt) {
        const int t  = tt ? t1 : t0;
        const int i  = t / 7, j = t - i * 7;
        const float* qp = qkv + wbase + (size_t)(i * 56 + j) * 512 + h * 8;
        const float* kp = qp + plane;
        float4 q0 = *(const float4*)(qp);
        float4 q1 = *(const float4*)(qp + 4);
        float4 q2 = *(const float4*)(qp + 16);
        float4 q3 = *(const float4*)(qp + 20);
        float4 k0 = *(const float4*)(kp);
        float4 k1 = *(const float4*)(kp + 4);
        float4 k2 = *(const float4*)(kp + 16);
        float4 k3 = *(const float4*)(kp + 20);
        qfr[tt][0] = pack8(q0, q1);  qfr[tt][1] = pack8(q2, q3);
        kfr[tt][0] = pack8(k0, k1);  kfr[tt][1] = pack8(k2, k3);
    }

    __syncthreads();

    // ---- QK^T swapped: S'[m][n] = K . Q^T ----
    f32x16 zer;
    #pragma unroll
    for (int i = 0; i < 16; ++i) zer[i] = 0.f;
    f32x16 acc[2][2];                    // [mt][nt]
    acc[0][0] = zer; acc[0][1] = zer; acc[1][0] = zer; acc[1][1] = zer;
    #pragma unroll
    for (int ks = 0; ks < 2; ++ks) {
        acc[0][0] = __builtin_amdgcn_mfma_f32_32x32x16_bf16(kfr[0][ks], qfr[0][ks], acc[0][0], 0, 0, 0);
        acc[0][1] = __builtin_amdgcn_mfma_f32_32x32x16_bf16(kfr[0][ks], qfr[1][ks], acc[0][1], 0, 0, 0);
        acc[1][0] = __builtin_amdgcn_mfma_f32_32x32x16_bf16(kfr[1][ks], qfr[0][ks], acc[1][0], 0, 0, 0);
        acc[1][1] = __builtin_amdgcn_mfma_f32_32x32x16_bf16(kfr[1][ks], qfr[1][ks], acc[1][1], 0, 0, 0);
    }

    // ---- logits + softmax per n-tile; pack UNNORMALIZED exp to bf16; stash 1/sum ----
    unsigned wpk[2][2][8];               // [nt][mt][g] : (p[ia], p[ia+4]) bf16x2
    #pragma unroll
    for (int nt = 0; nt < 2; ++nt) {
        const int n  = 32 * nt + ln;
        const int nc = n < NTOK ? n : NTOK - 1;
        const int i_n = nc / 7;
        const int tn  = nc + 6 * i_n + 84;          // (i*13+j) + 84
        float pl[2][16];
        float mx = -3.0e38f;
        #pragma unroll
        for (int mt = 0; mt < 2; ++mt) {
            #pragma unroll
            for (int r = 0; r < 16; ++r) {
                const int mb  = 32 * mt + (r & 3) + 8 * (r >> 2);
                const int m0  = mb, m1 = mb + 4;
                const int mc0 = m0 < NTOK ? m0 : NTOK - 1;
                const int mc1 = m1 < NTOK ? m1 : NTOK - 1;
                const int tm0 = mc0 + 6 * (mc0 / 7);   // compile-time
                const int tm1 = mc1 + 6 * (mc1 / 7);   // compile-time
                const int mc  = h ? mc1 : mc0;
                const int tm  = h ? tm1 : tm0;
                float s = acc[mt][nt][r] * SCALE + biasl[wave][tn - tm] + maskl[nc * NTOK + mc];
                const bool dead = h ? (m1 >= NTOK) : (m0 >= NTOK);
                s = dead ? -3.0e38f : s;
                pl[mt][r] = s;
                mx = fmaxf(mx, s);
            }
        }
        mx = fmaxf(mx, __shfl_xor(mx, 32));
        float sum = 0.f;
        #pragma unroll
        for (int mt = 0; mt < 2; ++mt) {
            #pragma unroll
            for (int g = 0; g < 8; ++g) {
                const int ia = (g < 4) ? g : g + 4;
                const float e0 = __expf(pl[mt][ia] - mx);
                const float e1 = __expf(pl[mt][ia + 4] - mx);
                sum += e0 + e1;
                wpk[nt][mt][g] = (unsigned)f2b(e0) | ((unsigned)f2b(e1) << 16);
            }
        }
        sum += __shfl_xor(sum, 32);
        if (h == 0 && n < NTOK)
            invl[wave][n] = 1.0f / sum;
    }

    // ---- PV: O[n][d] = sum_m P'[m][n] V[m][d]  (unnormalized P) ----
    f32x16 oacc[2];
    oacc[0] = zer; oacc[1] = zer;
    #pragma unroll
    for (int ksv = 0; ksv < 4; ++ksv) {
        short8 vf;
        #pragma unroll
        for (int j = 0; j < 8; ++j)
            vf[j] = (short)Vr[wave][16 * ksv + 8 * h + j][ln];
        const int mt = ksv >> 1;
        #pragma unroll
        for (int nt = 0; nt < 2; ++nt) {
            unsigned short alo[4], ahi[4];
            #pragma unroll
            for (int jj = 0; jj < 4; ++jj) {
                const unsigned W = wpk[nt][mt][(ksv & 1) * 4 + jj];
                const unsigned U = (unsigned)__shfl_xor((int)W, 32);
                alo[jj] = h ? (unsigned short)(U >> 16) : (unsigned short)(W & 0xffffu);
                ahi[jj] = h ? (unsigned short)(W >> 16) : (unsigned short)(U & 0xffffu);
            }
            short8 af;
            af[0] = (short)alo[0]; af[1] = (short)alo[1];
            af[2] = (short)alo[2]; af[3] = (short)alo[3];
            af[4] = (short)ahi[0]; af[5] = (short)ahi[1];
            af[6] = (short)ahi[2]; af[7] = (short)ahi[3];
            oacc[nt] = __builtin_amdgcn_mfma_f32_32x32x16_bf16(af, vf, oacc[nt], 0, 0, 0);
        }
    }

    // ---- store: D[row=n][col=d=ln], normalized by invl[row] (LDS broadcast) ----
    const size_t obase = ((size_t)win * NTOK) * DIM + head * HD + ln;
    #pragma unroll
    for (int nt = 0; nt < 2; ++nt) {
        #pragma unroll
        for (int r = 0; r < 16; ++r) {
            const int nb = 32 * nt + (r & 3) + 8 * (r >> 2);
            const int n  = h ? nb + 4 : nb;
            if (n < NTOK)
                out[obase + (size_t)n * DIM] = oacc[nt][r] * invl[wave][n];
        }
    }
}

extern "C" void kernel_launch(void* const* d_in, const int* in_sizes, int n_in,
                              void* d_out, int out_size, void* d_ws, size_t ws_size,
                              hipStream_t stream) {
    const float* qkv        = (const float*)d_in[0];
    const float* mask       = (const float*)d_in[1];
    const float* bias_table = (const float*)d_in[2];
    float* out = (float*)d_out;

    const int nblocks = 2048 * (NH / HPB);   // (window, head-group)
    winattn_mfma<<<nblocks, 256, 0, stream>>>(qkv, mask, bias_table, out);
}

// Round 6
// 197.385 us; speedup vs baseline: 8.8350x; 1.0067x over previous
//
#include <hip/hip_runtime.h>

#define NTOK 49
#define NH 16
#define DIM 512
#define HD 32
#define HPB 4
#define SCALE 0.17677669529663687f   // 32^-0.5

typedef __attribute__((ext_vector_type(8))) short short8;
typedef __attribute__((ext_vector_type(16))) float f32x16;

struct __attribute__((packed, aligned(4))) f4u { float x, y, z, w; };  // 4B-aligned float4

__device__ __forceinline__ unsigned short f2b(float x) {
    union { float f; unsigned u; } v; v.f = x;
    unsigned u = v.u;
    u += 0x7fffu + ((u >> 16) & 1u);          // RNE to bf16
    return (unsigned short)(u >> 16);
}

__device__ __forceinline__ float b2f(unsigned short b) {
    union { unsigned u; float f; } v; v.u = ((unsigned)b) << 16;
    return v.f;
}

__device__ __forceinline__ unsigned long long pack4(float4 v) {
    unsigned lo = (unsigned)f2b(v.x) | ((unsigned)f2b(v.y) << 16);
    unsigned hi = (unsigned)f2b(v.z) | ((unsigned)f2b(v.w) << 16);
    return (unsigned long long)lo | ((unsigned long long)hi << 32);
}

__device__ __forceinline__ short8 pack8s(float4 a, float4 b, float sc) {
    short8 r;
    r[0] = (short)f2b(a.x * sc); r[1] = (short)f2b(a.y * sc);
    r[2] = (short)f2b(a.z * sc); r[3] = (short)f2b(a.w * sc);
    r[4] = (short)f2b(b.x * sc); r[5] = (short)f2b(b.y * sc);
    r[6] = (short)f2b(b.z * sc); r[7] = (short)f2b(b.w * sc);
    return r;
}

// qkv: [3,32,56,56,512] f32 | mask: [64,49,49] f32 | bias_table: [169,16] f32
// out: [2048,49,512] f32
// Zero __syncthreads: every LDS region is wave-private; in-wave lgkmcnt ordering
// is sufficient. 16 independent wave-pipelines per CU.
__global__ __launch_bounds__(256, 4) void winattn_mfma(
    const float* __restrict__ qkv,
    const float* __restrict__ mask,
    const float* __restrict__ bias_table,
    float* __restrict__ out)
{
    __shared__ __align__(16) unsigned short Vr[HPB][64][32];     // 16 KB, V bf16 (own head)
    __shared__ __align__(8)  unsigned short maskw[HPB][2404];    // 19.2 KB, bf16 mask, per wave
    __shared__ float biasw[HPB][176];                            // 2.8 KB
    __shared__ float invl[HPB][64];                              // 1 KB

    const int bx   = blockIdx.x;
    const int win  = bx >> 2;
    const int hg   = bx & 3;
    const int tid  = threadIdx.x;
    const int wave = tid >> 6;
    const int lane = tid & 63;
    const int ln   = lane & 31;
    const int h    = lane >> 5;
    const int head = hg * HPB + wave;

    const int b  = win >> 6;
    const int w  = win & 63;
    const int wr = w >> 3, wc = w & 7;

    const size_t plane = (size_t)32 * 56 * 56 * 512;
    const size_t wbase = (((size_t)(b * 56 + wr * 7)) * 56 + wc * 7) * 512 + head * HD;

    // ---- Q/K fragment global loads issued FIRST (latency hides under staging) ----
    const int t0 = ln;
    const int t1 = (32 + ln <= 48) ? (32 + ln) : 48;
    float4 qv[2][4], kv[2][4];
    #pragma unroll
    for (int tt = 0; tt < 2; ++tt) {
        const int t  = tt ? t1 : t0;
        const int i  = t / 7, j = t - i * 7;
        const float* qp = qkv + wbase + (size_t)(i * 56 + j) * 512 + h * 8;
        const float* kp = qp + plane;
        qv[tt][0] = *(const float4*)(qp);
        qv[tt][1] = *(const float4*)(qp + 4);
        qv[tt][2] = *(const float4*)(qp + 16);
        qv[tt][3] = *(const float4*)(qp + 20);
        kv[tt][0] = *(const float4*)(kp);
        kv[tt][1] = *(const float4*)(kp + 4);
        kv[tt][2] = *(const float4*)(kp + 16);
        kv[tt][3] = *(const float4*)(kp + 20);
    }

    // ---- V staging: wave-private (own head), bf16, zero-pad tokens 49..63 ----
    #pragma unroll
    for (int e = 0; e < 8; ++e) {
        const int idx = e * 64 + lane;           // 512 slots: 64 tokens x 8 float4
        const int t   = idx >> 3;
        const int d4  = idx & 7;
        unsigned long long vz = 0;
        if (t < NTOK) {
            const int i = t / 7, j = t - i * 7;
            vz = pack4(*(const float4*)(qkv + 2 * plane + wbase
                                        + (size_t)(i * 56 + j) * 512 + d4 * 4));
        }
        *(unsigned long long*)&Vr[wave][t][d4 * 4] = vz;
    }

    // ---- mask staging: wave-private bf16 copy (2401 f32 -> bf16) ----
    const float* mrow = mask + (size_t)w * 2401;
    for (int e = lane; e < 600; e += 64) {
        f4u mv = *(const f4u*)(mrow + 4 * e);
        unsigned long long pk =
              (unsigned long long)f2b(mv.x)
            | ((unsigned long long)f2b(mv.y) << 16)
            | ((unsigned long long)f2b(mv.z) << 32)
            | ((unsigned long long)f2b(mv.w) << 48);
        *(unsigned long long*)&maskw[wave][4 * e] = pk;
    }
    if (lane == 0) maskw[wave][2400] = f2b(mrow[2400]);

    // ---- bias staging: wave-private column ----
    for (int r = lane; r < 169; r += 64)
        biasw[wave][r] = bias_table[r * NH + head];

    // ---- pack Q (pre-scaled) / K fragments ----
    short8 qfr[2][2], kfr[2][2];
    #pragma unroll
    for (int tt = 0; tt < 2; ++tt) {
        qfr[tt][0] = pack8s(qv[tt][0], qv[tt][1], SCALE);
        qfr[tt][1] = pack8s(qv[tt][2], qv[tt][3], SCALE);
        kfr[tt][0] = pack8s(kv[tt][0], kv[tt][1], 1.0f);
        kfr[tt][1] = pack8s(kv[tt][2], kv[tt][3], 1.0f);
    }

    // ---- QK^T swapped: S'[m][n] = K . (Q*SCALE)^T ----
    f32x16 zer;
    #pragma unroll
    for (int i = 0; i < 16; ++i) zer[i] = 0.f;
    f32x16 acc[2][2];                    // [mt][nt]
    acc[0][0] = zer; acc[0][1] = zer; acc[1][0] = zer; acc[1][1] = zer;
    #pragma unroll
    for (int ks = 0; ks < 2; ++ks) {
        acc[0][0] = __builtin_amdgcn_mfma_f32_32x32x16_bf16(kfr[0][ks], qfr[0][ks], acc[0][0], 0, 0, 0);
        acc[0][1] = __builtin_amdgcn_mfma_f32_32x32x16_bf16(kfr[0][ks], qfr[1][ks], acc[0][1], 0, 0, 0);
        acc[1][0] = __builtin_amdgcn_mfma_f32_32x32x16_bf16(kfr[1][ks], qfr[0][ks], acc[1][0], 0, 0, 0);
        acc[1][1] = __builtin_amdgcn_mfma_f32_32x32x16_bf16(kfr[1][ks], qfr[1][ks], acc[1][1], 0, 0, 0);
    }

    // ---- logits + softmax per n-tile; pack UNNORMALIZED exp to bf16; stash 1/sum ----
    unsigned wpk[2][2][8];               // [nt][mt][g] : (p[ia], p[ia+4]) bf16x2
    #pragma unroll
    for (int nt = 0; nt < 2; ++nt) {
        const int n  = 32 * nt + ln;
        const int nc = n < NTOK ? n : NTOK - 1;
        const int i_n = nc / 7;
        const int tn  = nc + 6 * i_n + 84;          // (i*13+j) + 84
        float pl[2][16];
        float mx = -3.0e38f;
        #pragma unroll
        for (int mt = 0; mt < 2; ++mt) {
            #pragma unroll
            for (int r = 0; r < 16; ++r) {
                const int mb  = 32 * mt + (r & 3) + 8 * (r >> 2);
                const int m0  = mb, m1 = mb + 4;
                const int mc0 = m0 < NTOK ? m0 : NTOK - 1;
                const int mc1 = m1 < NTOK ? m1 : NTOK - 1;
                const int tm0 = mc0 + 6 * (mc0 / 7);   // compile-time
                const int tm1 = mc1 + 6 * (mc1 / 7);   // compile-time
                const int mc  = h ? mc1 : mc0;
                const int tm  = h ? tm1 : tm0;
                float s = acc[mt][nt][r] + biasw[wave][tn - tm]
                        + b2f(maskw[wave][nc * NTOK + mc]);
                const bool dead = h ? (m1 >= NTOK) : (m0 >= NTOK);
                s = dead ? -3.0e38f : s;
                pl[mt][r] = s;
                mx = fmaxf(mx, s);
            }
        }
        mx = fmaxf(mx, __shfl_xor(mx, 32));
        float sum = 0.f;
        #pragma unroll
        for (int mt = 0; mt < 2; ++mt) {
            #pragma unroll
            for (int g = 0; g < 8; ++g) {
                const int ia = (g < 4) ? g : g + 4;
                const float e0 = __expf(pl[mt][ia] - mx);
                const float e1 = __expf(pl[mt][ia + 4] - mx);
                sum += e0 + e1;
                wpk[nt][mt][g] = (unsigned)f2b(e0) | ((unsigned)f2b(e1) << 16);
            }
        }
        sum += __shfl_xor(sum, 32);
        if (h == 0 && n < NTOK)
            invl[wave][n] = 1.0f / sum;
    }

    // ---- PV: O[n][d] = sum_m P'[m][n] V[m][d]  (unnormalized P) ----
    f32x16 oacc[2];
    oacc[0] = zer; oacc[1] = zer;
    #pragma unroll
    for (int ksv = 0; ksv < 4; ++ksv) {
        short8 vf;
        #pragma unroll
        for (int j = 0; j < 8; ++j)
            vf[j] = (short)Vr[wave][16 * ksv + 8 * h + j][ln];
        const int mt = ksv >> 1;
        #pragma unroll
        for (int nt = 0; nt < 2; ++nt) {
            unsigned short alo[4], ahi[4];
            #pragma unroll
            for (int jj = 0; jj < 4; ++jj) {
                const unsigned W = wpk[nt][mt][(ksv & 1) * 4 + jj];
                const unsigned U = (unsigned)__shfl_xor((int)W, 32);
                alo[jj] = h ? (unsigned short)(U >> 16) : (unsigned short)(W & 0xffffu);
                ahi[jj] = h ? (unsigned short)(W >> 16) : (unsigned short)(U & 0xffffu);
            }
            short8 af;
            af[0] = (short)alo[0]; af[1] = (short)alo[1];
            af[2] = (short)alo[2]; af[3] = (short)alo[3];
            af[4] = (short)ahi[0]; af[5] = (short)ahi[1];
            af[6] = (short)ahi[2]; af[7] = (short)ahi[3];
            oacc[nt] = __builtin_amdgcn_mfma_f32_32x32x16_bf16(af, vf, oacc[nt], 0, 0, 0);
        }
    }

    // ---- store: D[row=n][col=d=ln], normalized by invl[row] (wave-private LDS) ----
    const size_t obase = ((size_t)win * NTOK) * DIM + head * HD + ln;
    #pragma unroll
    for (int nt = 0; nt < 2; ++nt) {
        #pragma unroll
        for (int r = 0; r < 16; ++r) {
            const int nb = 32 * nt + (r & 3) + 8 * (r >> 2);
            const int n  = h ? nb + 4 : nb;
            if (n < NTOK)
                out[obase + (size_t)n * DIM] = oacc[nt][r] * invl[wave][n];
        }
    }
}

extern "C" void kernel_launch(void* const* d_in, const int* in_sizes, int n_in,
                              void* d_out, int out_size, void* d_ws, size_t ws_size,
                              hipStream_t stream) {
    const float* qkv        = (const float*)d_in[0];
    const float* mask       = (const float*)d_in[1];
    const float* bias_table = (const float*)d_in[2];
    float* out = (float*)d_out;

    const int nblocks = 2048 * (NH / HPB);   // (window, head-group)
    winattn_mfma<<<nblocks, 256, 0, stream>>>(qkv, mask, bias_table, out);
}